// Round 10
// baseline (336.884 us; speedup 1.0000x reference)
//
#include <hip/hip_runtime.h>
#include <hip/hip_bf16.h>

typedef __attribute__((ext_vector_type(8))) __bf16 bf16x8;
typedef __attribute__((ext_vector_type(4))) float f32x4;

#define NN 100000
#define NE 1600000
#define NBUCK 1563        // buckets of 64 nodes
#define ECHUNK 200000     // NE/8 edges per chunk-group
#define MAXE 2048         // LDS edge-slice capacity per pass

__device__ __forceinline__ float bflo(unsigned w) { return __uint_as_float(w << 16); }
__device__ __forceinline__ float bfhi(unsigned w) { return __uint_as_float(w & 0xffff0000u); }

// ---------------- converts: weights (transpose+bf16) and x (bf16) ----------------
__global__ void convert_kernel(const float* __restrict__ W1, const float* __restrict__ W2,
                               __bf16* __restrict__ W1T, __bf16* __restrict__ W2T,
                               const float4* __restrict__ x4, uint2* __restrict__ xb) {
    int tid = blockIdx.x * 256 + threadIdx.x;
    if (tid < 128 * 256) {
        int k1 = tid >> 8, n1 = tid & 255;             // W1 is [128][256]
        W1T[n1 * 128 + k1] = (__bf16)W1[tid];
        int k2 = tid >> 7, n2 = tid & 127;             // W2 is [256][128]
        W2T[n2 * 256 + k2] = (__bf16)W2[tid];
    } else {
        int i = tid - 128 * 256;
        if (i < NN * 32) {                             // n4 = NN*128/4
            float4 v = x4[i];
            __bf16 b0 = (__bf16)v.x, b1 = (__bf16)v.y, b2 = (__bf16)v.z, b3 = (__bf16)v.w;
            uint2 o;
            o.x = (unsigned)*(unsigned short*)&b0 | ((unsigned)*(unsigned short*)&b1 << 16);
            o.y = (unsigned)*(unsigned short*)&b2 | ((unsigned)*(unsigned short*)&b3 << 16);
            xb[i] = o;
        }
    }
}

// ---------------- bucket-granular CSR build (bucket = 64 nodes) ----------------
__global__ void hist_bucket8(const int* __restrict__ edst, int* __restrict__ cnt8) {
    int grp  = blockIdx.x & 7;
    int blk  = blockIdx.x >> 3;
    int nblk = gridDim.x >> 3;
    int* my = cnt8 + grp * NBUCK;
    int lo = grp * ECHUNK, hi = lo + ECHUNK;
    if (hi > NE) hi = NE;
    for (int e = lo + blk * 256 + threadIdx.x; e < hi; e += nblk * 256)
        atomicAdd(&my[edst[e] >> 6], 1);
}

__global__ void scan_all(const int* __restrict__ cnt8, int* __restrict__ bucket_off,
                         int* __restrict__ cursor8) {
    __shared__ int sm[256];
    __shared__ int carry;
    int t = threadIdx.x;
    if (t == 0) carry = 0;
    __syncthreads();
    for (int base = 0; base < NBUCK; base += 256) {
        int b = base + t;
        int c[8]; int tot = 0;
        if (b < NBUCK) {
#pragma unroll
            for (int g = 0; g < 8; ++g) { c[g] = cnt8[g * NBUCK + b]; tot += c[g]; }
        }
        sm[t] = tot; __syncthreads();
        for (int off = 1; off < 256; off <<= 1) {
            int add = (t >= off) ? sm[t - off] : 0;
            __syncthreads();
            sm[t] += add;
            __syncthreads();
        }
        int excl = carry + sm[t] - tot;
        if (b < NBUCK) {
            bucket_off[b] = excl;
            int run = excl;
#pragma unroll
            for (int g = 0; g < 8; ++g) { cursor8[g * NBUCK + b] = run; run += c[g]; }
        }
        __syncthreads();
        if (t == 255) carry += sm[255];
        __syncthreads();
    }
    if (t == 0) bucket_off[NBUCK] = NE;
}

// pairs[pos] = {(src<<8)|(dst&63), val_bits}; 1563 write streams per group
__global__ void reorder_bucket8(const int* __restrict__ esrc, const int* __restrict__ edst,
                                const float* __restrict__ ev,
                                int* cursor8, int2* __restrict__ pairs) {
    int grp  = blockIdx.x & 7;
    int blk  = blockIdx.x >> 3;
    int nblk = gridDim.x >> 3;
    int* cur = cursor8 + grp * NBUCK;
    int lo = grp * ECHUNK, hi = lo + ECHUNK;
    if (hi > NE) hi = NE;
    for (int e = lo + blk * 256 + threadIdx.x; e < hi; e += nblk * 256) {
        int d = edst[e];
        int s = esrc[e];
        float v = ev[e];
        int pos = atomicAdd(&cur[d >> 6], 1);
        int2 p; p.x = (s << 8) | (d & 63); p.y = __float_as_int(v);
        pairs[pos] = p;
    }
}

// ---------------- FUSED: LDS-sort + gather + 2-layer MFMA MLP, one block per 64-node bucket ----
// 1024 threads = 16 waves. LDS overlays: {raw,srt} (sort/gather) then {Atile,Hl} (MLP).
__global__ __launch_bounds__(1024) void gather_mlp_kernel(const unsigned* __restrict__ xb,
                                                          const int* __restrict__ bucket_off,
                                                          const int2* __restrict__ pairs,
                                                          const float* __restrict__ eps,
                                                          const __bf16* __restrict__ W1T,
                                                          const __bf16* __restrict__ W2T,
                                                          const float* __restrict__ b1,
                                                          const float* __restrict__ b2,
                                                          float* __restrict__ out) {
    __shared__ __attribute__((aligned(16))) char smem[51200];
    int2*     raw = (int2*)smem;                    // [2048]  bytes 0..16383
    int2*     srt = (int2*)(smem + 16384);          // [2048]  bytes 16384..32767
    unsigned* At  = (unsigned*)smem;                // [64][68] bytes 0..17407 (after gather)
    __bf16*   Hl  = (__bf16*)(smem + 17408);        // [64][264] bytes 17408..51199
    __shared__ int rcnt[64], rofs[64], rcur[64];

    const int t = threadIdx.x;
    const int b = blockIdx.x;
    const int beg = bucket_off[b], end = bucket_off[b + 1];
    const int wave = t >> 6, lane = t & 63;
    const int hw = lane >> 5, l32 = lane & 31;
    const char* xbase = (const char*)xb + l32 * 8;

    float acc[4][4];
#pragma unroll
    for (int i = 0; i < 4; ++i) { acc[i][0] = acc[i][1] = acc[i][2] = acc[i][3] = 0.f; }

    // ---- sort + gather (chunked) ----
    for (int cbeg = beg; cbeg < end; cbeg += MAXE) {
        int m = end - cbeg; if (m > MAXE) m = MAXE;
        if (t < 64) rcnt[t] = 0;
        __syncthreads();
        for (int i = t; i < m; i += 1024) {
            int2 p = pairs[cbeg + i];
            raw[i] = p;
            atomicAdd(&rcnt[p.x & 63], 1);
        }
        __syncthreads();
        if (t < 64) {                       // wave 0: exclusive scan of 64 counts
            int v = rcnt[t], s = v;
#pragma unroll
            for (int off = 1; off < 64; off <<= 1) {
                int u = __shfl_up(s, off);
                if (t >= off) s += u;
            }
            rofs[t] = s - v; rcur[t] = s - v;
        }
        __syncthreads();
        for (int i = t; i < m; i += 1024) {
            int2 p = raw[i];
            int pos = atomicAdd(&rcur[p.x & 63], 1);
            int2 q; q.x = p.x & 0xffffff00; q.y = p.y;   // {src byte-offset, val}
            srt[pos] = q;
        }
        __syncthreads();
        // gather: wave handles rows wave*4 .. wave*4+3; half-waves interleave
#pragma unroll
        for (int i = 0; i < 4; ++i) {
            const int r = wave * 4 + i;
            const int je = rofs[r] + rcnt[r];
            int j = rofs[r] + hw;
            for (; j + 2 < je; j += 4) {
                int2 e0 = srt[j], e1 = srt[j + 2];
                uint2 w0 = *(const uint2*)(xbase + e0.x);
                uint2 w1 = *(const uint2*)(xbase + e1.x);
                float v0 = __int_as_float(e0.y), v1 = __int_as_float(e1.y);
                acc[i][0] = fmaf(v0, bflo(w0.x), acc[i][0]);
                acc[i][1] = fmaf(v0, bfhi(w0.x), acc[i][1]);
                acc[i][2] = fmaf(v0, bflo(w0.y), acc[i][2]);
                acc[i][3] = fmaf(v0, bfhi(w0.y), acc[i][3]);
                acc[i][0] = fmaf(v1, bflo(w1.x), acc[i][0]);
                acc[i][1] = fmaf(v1, bfhi(w1.x), acc[i][1]);
                acc[i][2] = fmaf(v1, bflo(w1.y), acc[i][2]);
                acc[i][3] = fmaf(v1, bfhi(w1.y), acc[i][3]);
            }
            for (; j < je; j += 2) {
                int2 e0 = srt[j];
                uint2 w0 = *(const uint2*)(xbase + e0.x);
                float v0 = __int_as_float(e0.y);
                acc[i][0] = fmaf(v0, bflo(w0.x), acc[i][0]);
                acc[i][1] = fmaf(v0, bfhi(w0.x), acc[i][1]);
                acc[i][2] = fmaf(v0, bflo(w0.y), acc[i][2]);
                acc[i][3] = fmaf(v0, bfhi(w0.y), acc[i][3]);
            }
        }
        __syncthreads();
    }

    // ---- combine half-waves, add self-loop, write bf16 A-tile to LDS ----
#pragma unroll
    for (int i = 0; i < 4; ++i) {
        float a0 = acc[i][0], a1 = acc[i][1], a2 = acc[i][2], a3 = acc[i][3];
        a0 += __shfl_xor(a0, 32); a1 += __shfl_xor(a1, 32);
        a2 += __shfl_xor(a2, 32); a3 += __shfl_xor(a3, 32);
        if (hw == 0) {
            const int r = wave * 4 + i;
            const int n = b * 64 + r;
            unsigned p0 = 0, p1 = 0;
            if (n < NN) {
                uint2 ws = *(const uint2*)(xbase + (size_t)n * 256);
                float sc = 1.0f + eps[0];
                a0 = fmaf(sc, bflo(ws.x), a0); a1 = fmaf(sc, bfhi(ws.x), a1);
                a2 = fmaf(sc, bflo(ws.y), a2); a3 = fmaf(sc, bfhi(ws.y), a3);
                __bf16 c0 = (__bf16)a0, c1 = (__bf16)a1, c2 = (__bf16)a2, c3 = (__bf16)a3;
                p0 = (unsigned)*(unsigned short*)&c0 | ((unsigned)*(unsigned short*)&c1 << 16);
                p1 = (unsigned)*(unsigned short*)&c2 | ((unsigned)*(unsigned short*)&c3 << 16);
            }
            At[r * 68 + l32 * 2]     = p0;
            At[r * 68 + l32 * 2 + 1] = p1;
        }
    }
    __syncthreads();

    const int l15 = lane & 15, lhi = lane >> 4;

    // ---- stage 1: Hl = relu(A @ W1 + b1); wave owns 16 cols of 256 ----
    {
        f32x4 acc1[4] = {};
        const int n = wave * 16 + l15;
        const __bf16* w1p = W1T + (size_t)n * 128;
#pragma unroll
        for (int ks = 0; ks < 4; ++ks) {
            const int k0 = ks * 32 + lhi * 8;
            bf16x8 bn = *(const bf16x8*)(w1p + k0);
#pragma unroll
            for (int mt = 0; mt < 4; ++mt) {
                bf16x8 am = *(const bf16x8*)(At + (mt * 16 + l15) * 68 + ks * 16 + lhi * 4);
                acc1[mt] = __builtin_amdgcn_mfma_f32_16x16x32_bf16(am, bn, acc1[mt], 0, 0, 0);
            }
        }
        float bias = b1[n];
#pragma unroll
        for (int mt = 0; mt < 4; ++mt)
#pragma unroll
            for (int r = 0; r < 4; ++r) {
                float h = acc1[mt][r] + bias;
                Hl[(mt * 16 + lhi * 4 + r) * 264 + n] = (__bf16)fmaxf(h, 0.0f);
            }
    }
    __syncthreads();

    // ---- stage 2: out = Hl @ W2 + b2; wave owns 2 of 32 (mt,nt) 16x16 tiles ----
    {
        f32x4 acc2[2] = {};
#pragma unroll
        for (int ks = 0; ks < 8; ++ks) {
            const int k0 = ks * 32 + lhi * 8;
#pragma unroll
            for (int a = 0; a < 2; ++a) {
                const int idx = wave * 2 + a;
                const int mt = idx >> 3, nt = idx & 7;
                bf16x8 ha = *(const bf16x8*)(Hl + (mt * 16 + l15) * 264 + k0);
                bf16x8 wb = *(const bf16x8*)(W2T + (size_t)(nt * 16 + l15) * 256 + k0);
                acc2[a] = __builtin_amdgcn_mfma_f32_16x16x32_bf16(ha, wb, acc2[a], 0, 0, 0);
            }
        }
#pragma unroll
        for (int a = 0; a < 2; ++a) {
            const int idx = wave * 2 + a;
            const int mt = idx >> 3, nt = idx & 7;
            const int col = nt * 16 + l15;
            float bias = b2[col];
#pragma unroll
            for (int r = 0; r < 4; ++r) {
                int row = b * 64 + mt * 16 + lhi * 4 + r;
                if (row < NN) out[(size_t)row * 128 + col] = acc2[a][r] + bias;
            }
        }
    }
}

// ---------------- fallback path (atomic scatter, fp32 AX in d_out) ----------------
__global__ void init_ax_kernel(const float4* __restrict__ x, float4* __restrict__ AX,
                               const float* __restrict__ eps, int n4) {
    int i = blockIdx.x * blockDim.x + threadIdx.x;
    if (i >= n4) return;
    float s = 1.0f + eps[0];
    float4 v = x[i];
    v.x *= s; v.y *= s; v.z *= s; v.w *= s;
    AX[i] = v;
}

__global__ void scatter_kernel(const float2* __restrict__ x2, const float* __restrict__ ev,
                               const int* __restrict__ esrc, const int* __restrict__ edst,
                               float* AX) {
    unsigned gid = blockIdx.x * 256u + threadIdx.x;
    unsigned e = gid >> 6;
    unsigned lane = gid & 63u;
    if (e >= NE) return;
    float v = ev[e];
    int s = esrc[e], d = edst[e];
    float2 xv = x2[(size_t)s * 64 + lane];
    float* dstp = AX + (size_t)d * 128 + lane * 2;
    atomicAdd(dstp,     v * xv.x);
    atomicAdd(dstp + 1, v * xv.y);
}

__global__ __launch_bounds__(256) void mlp_kernel(const float* A,
                                                  const __bf16* __restrict__ W1T,
                                                  const __bf16* __restrict__ W2T,
                                                  const float* __restrict__ b1,
                                                  const float* __restrict__ b2,
                                                  float* out) {
    __shared__ __bf16 Hl[64][264];
    const int wave = threadIdx.x >> 6;
    const int lane = threadIdx.x & 63;
    const int l15  = lane & 15;
    const int lhi  = lane >> 4;
    const int rowbase = blockIdx.x * 64;

    f32x4 acc1[4][4] = {};
#pragma unroll
    for (int ks = 0; ks < 4; ++ks) {
        const int k0 = ks * 32 + lhi * 8;
        bf16x8 am[4], bn[4];
#pragma unroll
        for (int mt = 0; mt < 4; ++mt) {
            int row = rowbase + mt * 16 + l15;
            if (row >= NN) row = NN - 1;
            const float4* ap = (const float4*)(A + (size_t)row * 128 + k0);
            float4 f0 = ap[0], f1 = ap[1];
            bf16x8 a;
            a[0]=(__bf16)f0.x; a[1]=(__bf16)f0.y; a[2]=(__bf16)f0.z; a[3]=(__bf16)f0.w;
            a[4]=(__bf16)f1.x; a[5]=(__bf16)f1.y; a[6]=(__bf16)f1.z; a[7]=(__bf16)f1.w;
            am[mt] = a;
        }
#pragma unroll
        for (int nt = 0; nt < 4; ++nt) {
            int n = wave * 64 + nt * 16 + l15;
            bn[nt] = *(const bf16x8*)(W1T + (size_t)n * 128 + k0);
        }
#pragma unroll
        for (int mt = 0; mt < 4; ++mt)
#pragma unroll
            for (int nt = 0; nt < 4; ++nt)
                acc1[mt][nt] = __builtin_amdgcn_mfma_f32_16x16x32_bf16(am[mt], bn[nt], acc1[mt][nt], 0, 0, 0);
    }
#pragma unroll
    for (int nt = 0; nt < 4; ++nt) {
        int n = wave * 64 + nt * 16 + l15;
        float bias = b1[n];
#pragma unroll
        for (int mt = 0; mt < 4; ++mt)
#pragma unroll
            for (int r = 0; r < 4; ++r) {
                float h = acc1[mt][nt][r] + bias;
                Hl[mt * 16 + lhi * 4 + r][n] = (__bf16)fmaxf(h, 0.0f);
            }
    }
    __syncthreads();

    f32x4 acc2[4][2] = {};
#pragma unroll
    for (int ks = 0; ks < 8; ++ks) {
        const int k0 = ks * 32 + lhi * 8;
        bf16x8 ha[4], wb[2];
#pragma unroll
        for (int mt = 0; mt < 4; ++mt)
            ha[mt] = *(const bf16x8*)(&Hl[mt * 16 + l15][k0]);
#pragma unroll
        for (int nt = 0; nt < 2; ++nt) {
            int n = wave * 32 + nt * 16 + l15;
            wb[nt] = *(const bf16x8*)(W2T + (size_t)n * 256 + k0);
        }
#pragma unroll
        for (int mt = 0; mt < 4; ++mt)
#pragma unroll
            for (int nt = 0; nt < 2; ++nt)
                acc2[mt][nt] = __builtin_amdgcn_mfma_f32_16x16x32_bf16(ha[mt], wb[nt], acc2[mt][nt], 0, 0, 0);
    }
#pragma unroll
    for (int nt = 0; nt < 2; ++nt) {
        int n = wave * 32 + nt * 16 + l15;
        float bias = b2[n];
#pragma unroll
        for (int mt = 0; mt < 4; ++mt)
#pragma unroll
            for (int r = 0; r < 4; ++r) {
                int row = rowbase + mt * 16 + lhi * 4 + r;
                if (row < NN) out[(size_t)row * 128 + n] = acc2[mt][nt][r] + bias;
            }
    }
}

extern "C" void kernel_launch(void* const* d_in, const int* in_sizes, int n_in,
                              void* d_out, int out_size, void* d_ws, size_t ws_size,
                              hipStream_t stream) {
    const float* x    = (const float*)d_in[0];
    const float* ev   = (const float*)d_in[1];
    const float* W1   = (const float*)d_in[2];
    const float* b1   = (const float*)d_in[3];
    const float* W2   = (const float*)d_in[4];
    const float* b2   = (const float*)d_in[5];
    const float* eps  = (const float*)d_in[6];
    const int*   esrc = (const int*)d_in[7];
    const int*   edst = (const int*)d_in[8];
    float* out = (float*)d_out;

    char* ws = (char*)d_ws;
    size_t off = 0;
    auto alloc = [&](size_t bytes) { void* p = ws + off; off += (bytes + 511) & ~size_t(511); return p; };

    __bf16* W1T     = (__bf16*)alloc(128 * 256 * sizeof(__bf16));
    __bf16* W2T     = (__bf16*)alloc(128 * 256 * sizeof(__bf16));
    int* cnt8       = (int*)  alloc((size_t)8 * NBUCK * sizeof(int));
    int* bucket_off = (int*)  alloc((NBUCK + 1) * sizeof(int));
    int* cursor8    = (int*)  alloc((size_t)8 * NBUCK * sizeof(int));
    int2* pairs     = (int2*) alloc((size_t)NE * sizeof(int2));
    unsigned* xb    = (unsigned*)alloc((size_t)NN * 64 * sizeof(unsigned));   // bf16 x
    bool csr_ok = (off <= ws_size);

    if (csr_ok) {
        int cblocks = 128 + (NN * 32 + 255) / 256;   // weights + x converts
        convert_kernel<<<cblocks, 256, 0, stream>>>(W1, W2, W1T, W2T, (const float4*)x, (uint2*)xb);
        hipMemsetAsync(cnt8, 0, (size_t)8 * NBUCK * sizeof(int), stream);
        hist_bucket8<<<2048, 256, 0, stream>>>(edst, cnt8);
        scan_all<<<1, 256, 0, stream>>>(cnt8, bucket_off, cursor8);
        reorder_bucket8<<<2048, 256, 0, stream>>>(esrc, edst, ev, cursor8, pairs);
        gather_mlp_kernel<<<NBUCK, 1024, 0, stream>>>(xb, bucket_off, pairs, eps,
                                                      W1T, W2T, b1, b2, out);
    } else {
        // fallback: atomic scatter path (fp32 AX in d_out)
        __bf16* W1Tf = (__bf16*)ws;
        __bf16* W2Tf = W1Tf + 128 * 256;
        convert_kernel<<<128, 256, 0, stream>>>(W1, W2, W1Tf, W2Tf, (const float4*)x, (uint2*)nullptr);
        int n4 = NN * 128 / 4;
        init_ax_kernel<<<(n4 + 255) / 256, 256, 0, stream>>>((const float4*)x, (float4*)out, eps, n4);
        scatter_kernel<<<(NE * 64u) / 256u, 256, 0, stream>>>((const float2*)x, ev, esrc, edst, out);
        int nblk = (NN + 63) / 64;
        mlp_kernel<<<nblk, 256, 0, stream>>>(out, W1Tf, W2Tf, b1, b2, out);
    }
}

// Round 11
// 283.784 us; speedup vs baseline: 1.1871x; 1.1871x over previous
//
#include <hip/hip_runtime.h>
#include <hip/hip_bf16.h>
#include <type_traits>

typedef __attribute__((ext_vector_type(8))) __bf16 bf16x8;
typedef __attribute__((ext_vector_type(4))) float f32x4;

#define NN 100000
#define NE 1600000
#define NB1 391          // ceil(NN/256)
#define XRNG 12500       // NN/8 nodes per XCD group (reorder dst ranges)
#define ECHUNK 200000    // NE/8 edges per group (hist chunks)

// ---------------- converts: weights (transpose+bf16) and x (bf16), one kernel ----------------
__global__ void convert_kernel(const float* __restrict__ W1, const float* __restrict__ W2,
                               __bf16* __restrict__ W1T, __bf16* __restrict__ W2T,
                               const float4* __restrict__ x4, uint2* __restrict__ xb) {
    int tid = blockIdx.x * 256 + threadIdx.x;
    if (tid < 128 * 256) {
        int k1 = tid >> 8, n1 = tid & 255;             // W1 is [128][256]
        W1T[n1 * 128 + k1] = (__bf16)W1[tid];
        int k2 = tid >> 7, n2 = tid & 127;             // W2 is [256][128]
        W2T[n2 * 256 + k2] = (__bf16)W2[tid];
    } else {
        int i = tid - 128 * 256;
        if (i < NN * 32) {                             // n4 = NN*128/4
            float4 v = x4[i];
            __bf16 b0 = (__bf16)v.x, b1 = (__bf16)v.y, b2 = (__bf16)v.z, b3 = (__bf16)v.w;
            uint2 o;
            o.x = (unsigned)*(unsigned short*)&b0 | ((unsigned)*(unsigned short*)&b1 << 16);
            o.y = (unsigned)*(unsigned short*)&b2 | ((unsigned)*(unsigned short*)&b3 << 16);
            xb[i] = o;
        }
    }
}

// ---------------- CSR build ----------------
// Single-pass hist: group g = blockIdx&7 scans edge chunk g into PRIVATE cnt8[g*NN..]
__global__ void hist_kernel8(const int* __restrict__ edst, int* __restrict__ cnt8) {
    int grp  = blockIdx.x & 7;
    int blk  = blockIdx.x >> 3;
    int nblk = gridDim.x >> 3;
    int* mycnt = cnt8 + grp * NN;
    int lo = grp * ECHUNK, hi = lo + ECHUNK;
    if (hi > NE) hi = NE;
    for (int e = lo + blk * 256 + threadIdx.x; e < hi; e += nblk * 256)
        atomicAdd(&mycnt[edst[e]], 1);
}

__global__ void scan_block_sums(const int* __restrict__ cnt8, int* __restrict__ bsum) {
    __shared__ int sm[256];
    int i = blockIdx.x * 256 + threadIdx.x;
    int v = 0;
    if (i < NN) {
#pragma unroll
        for (int g = 0; g < 8; ++g) v += cnt8[g * NN + i];
    }
    sm[threadIdx.x] = v;
    __syncthreads();
    for (int s = 128; s > 0; s >>= 1) {
        if (threadIdx.x < s) sm[threadIdx.x] += sm[threadIdx.x + s];
        __syncthreads();
    }
    if (threadIdx.x == 0) bsum[blockIdx.x] = sm[0];
}

__global__ void scan_partials(const int* __restrict__ bsum, int* __restrict__ boff) {
    __shared__ int sm[512];
    int t = threadIdx.x;
    int v = (t < NB1) ? bsum[t] : 0;
    sm[t] = v; __syncthreads();
    for (int off = 1; off < 512; off <<= 1) {
        int add = (t >= off) ? sm[t - off] : 0;
        __syncthreads();
        sm[t] += add;
        __syncthreads();
    }
    if (t < NB1) boff[t] = sm[t] - v;   // exclusive
}

__global__ void scan_write_offsets(const int* __restrict__ cnt8, const int* __restrict__ boff,
                                   int* __restrict__ node_off, int* __restrict__ cursor) {
    __shared__ int sm[256];
    int t = threadIdx.x;
    int i = blockIdx.x * 256 + t;
    int v = 0;
    if (i < NN) {
#pragma unroll
        for (int g = 0; g < 8; ++g) v += cnt8[g * NN + i];
    }
    sm[t] = v; __syncthreads();
    for (int off = 1; off < 256; off <<= 1) {
        int add = (t >= off) ? sm[t - off] : 0;
        __syncthreads();
        sm[t] += add;
        __syncthreads();
    }
    int excl = sm[t] - v + boff[blockIdx.x];
    if (i < NN) { node_off[i] = excl; cursor[i] = excl; }
    if (i == 0) node_off[NN] = NE;
}

// XCD-partitioned scatter: pairs[pos] = {src_byte_offset, val_bits}
__global__ void reorder_xcd_kernel(const int* __restrict__ esrc, const int* __restrict__ edst,
                                   const float* __restrict__ ev,
                                   int* cursor, int2* __restrict__ pairs) {
    int grp  = blockIdx.x & 7;
    int blk  = blockIdx.x >> 3;
    int nblk = gridDim.x >> 3;
    int lo = grp * XRNG, hi = lo + XRNG;
    for (int e = blk * 256 + threadIdx.x; e < NE; e += nblk * 256) {
        int d = edst[e];
        int s = esrc[e];           // unconditional coalesced loads
        float v = ev[e];
        if (d >= lo && d < hi) {
            int pos = atomicAdd(&cursor[d], 1);
            int2 p; p.x = s << 8;  // pre-scaled: byte offset of row in xb (256B rows)
            p.y = __float_as_int(v);
            pairs[pos] = p;
        }
    }
}

// ---------------- per-node gather reduce (bf16 x, contiguous half-ranges, int4 meta) ---------
__device__ __forceinline__ float bflo(unsigned w) { return __uint_as_float(w << 16); }
__device__ __forceinline__ float bfhi(unsigned w) { return __uint_as_float(w & 0xffff0000u); }

__global__ __launch_bounds__(256) void gather_reduce_kernel(const unsigned* __restrict__ xb,
                                                            const int* __restrict__ node_off,
                                                            const int2* __restrict__ pairs,
                                                            const float* __restrict__ eps,
                                                            uint2* __restrict__ AXb) {
    unsigned gid = blockIdx.x * 256u + threadIdx.x;
    unsigned n = gid >> 6, lane = gid & 63u;
    if (n >= NN) return;
    const unsigned hw = lane >> 5, l32 = lane & 31u;
    const int beg = node_off[n], end = node_off[n + 1];
    const int cnt = end - beg;
    const int half = (cnt + 1) >> 1;
    const char* xbase = (const char*)xb + l32 * 8;   // this lane's 8B slot within any row
    float a0 = 0.f, a1 = 0.f, a2 = 0.f, a3 = 0.f;

    // half-wave hw owns contiguous range [jb, je)
    int jb = beg + (hw ? half : 0);
    int je = hw ? end : beg + half;
    int j = jb;
    if (j < je && (j & 1)) {                         // parity peel -> int4 alignment
        int2 p = pairs[j];
        uint2 w = *(const uint2*)(xbase + p.x);
        float v = __int_as_float(p.y);
        a0 = fmaf(v, bflo(w.x), a0); a1 = fmaf(v, bfhi(w.x), a1);
        a2 = fmaf(v, bflo(w.y), a2); a3 = fmaf(v, bfhi(w.y), a3);
        ++j;
    }
    for (; j + 3 < je; j += 4) {                     // 4 edges, 2 aligned int4 meta loads
        int4 m01 = *(const int4*)(pairs + j);
        int4 m23 = *(const int4*)(pairs + j + 2);
        uint2 w0 = *(const uint2*)(xbase + m01.x);
        uint2 w1 = *(const uint2*)(xbase + m01.z);
        uint2 w2 = *(const uint2*)(xbase + m23.x);
        uint2 w3 = *(const uint2*)(xbase + m23.z);
        float v0 = __int_as_float(m01.y), v1 = __int_as_float(m01.w);
        float v2 = __int_as_float(m23.y), v3 = __int_as_float(m23.w);
        a0 = fmaf(v0, bflo(w0.x), a0); a1 = fmaf(v0, bfhi(w0.x), a1);
        a2 = fmaf(v0, bflo(w0.y), a2); a3 = fmaf(v0, bfhi(w0.y), a3);
        a0 = fmaf(v1, bflo(w1.x), a0); a1 = fmaf(v1, bfhi(w1.x), a1);
        a2 = fmaf(v1, bflo(w1.y), a2); a3 = fmaf(v1, bfhi(w1.y), a3);
        a0 = fmaf(v2, bflo(w2.x), a0); a1 = fmaf(v2, bfhi(w2.x), a1);
        a2 = fmaf(v2, bflo(w2.y), a2); a3 = fmaf(v2, bfhi(w2.y), a3);
        a0 = fmaf(v3, bflo(w3.x), a0); a1 = fmaf(v3, bfhi(w3.x), a1);
        a2 = fmaf(v3, bflo(w3.y), a2); a3 = fmaf(v3, bfhi(w3.y), a3);
    }
    for (; j < je; ++j) {
        int2 p = pairs[j];
        uint2 w = *(const uint2*)(xbase + p.x);
        float v = __int_as_float(p.y);
        a0 = fmaf(v, bflo(w.x), a0); a1 = fmaf(v, bfhi(w.x), a1);
        a2 = fmaf(v, bflo(w.y), a2); a3 = fmaf(v, bfhi(w.y), a3);
    }
    // combine the two half-wave partials
    a0 += __shfl_xor(a0, 32); a1 += __shfl_xor(a1, 32);
    a2 += __shfl_xor(a2, 32); a3 += __shfl_xor(a3, 32);
    if (hw == 0) {
        uint2 ws = *(const uint2*)(xbase + (size_t)n * 256);
        float sc = 1.0f + eps[0];
        a0 = fmaf(sc, bflo(ws.x), a0); a1 = fmaf(sc, bfhi(ws.x), a1);
        a2 = fmaf(sc, bflo(ws.y), a2); a3 = fmaf(sc, bfhi(ws.y), a3);
        __bf16 b0 = (__bf16)a0, b1 = (__bf16)a1, b2 = (__bf16)a2, b3 = (__bf16)a3;
        uint2 o;
        o.x = (unsigned)*(unsigned short*)&b0 | ((unsigned)*(unsigned short*)&b1 << 16);
        o.y = (unsigned)*(unsigned short*)&b2 | ((unsigned)*(unsigned short*)&b3 << 16);
        AXb[(size_t)n * 32 + l32] = o;
    }
}

// ---------------- fallback path (atomic scatter, fp32 AX in d_out) ----------------
__global__ void init_ax_kernel(const float4* __restrict__ x, float4* __restrict__ AX,
                               const float* __restrict__ eps, int n4) {
    int i = blockIdx.x * blockDim.x + threadIdx.x;
    if (i >= n4) return;
    float s = 1.0f + eps[0];
    float4 v = x[i];
    v.x *= s; v.y *= s; v.z *= s; v.w *= s;
    AX[i] = v;
}

__global__ void scatter_kernel(const float2* __restrict__ x2, const float* __restrict__ ev,
                               const int* __restrict__ esrc, const int* __restrict__ edst,
                               float* AX) {
    unsigned gid = blockIdx.x * 256u + threadIdx.x;
    unsigned e = gid >> 6;
    unsigned lane = gid & 63u;
    if (e >= NE) return;
    float v = ev[e];
    int s = esrc[e], d = edst[e];
    float2 xv = x2[(size_t)s * 64 + lane];
    float* dstp = AX + (size_t)d * 128 + lane * 2;
    atomicAdd(dstp,     v * xv.x);
    atomicAdd(dstp + 1, v * xv.y);
}

// ---------------- fused 2-layer MLP: out = relu(A@W1+b1)@W2+b2, A is bf16 or fp32 ----------------
template <typename AT>
__global__ __launch_bounds__(256) void mlp_kernel(const AT* A,
                                                  const __bf16* __restrict__ W1T,
                                                  const __bf16* __restrict__ W2T,
                                                  const float* __restrict__ b1,
                                                  const float* __restrict__ b2,
                                                  float* out) {
    __shared__ __bf16 Hl[64][264];

    const int wave = threadIdx.x >> 6;
    const int lane = threadIdx.x & 63;
    const int l15  = lane & 15;
    const int lhi  = lane >> 4;
    const int rowbase = blockIdx.x * 64;

    f32x4 acc1[4][4] = {};
#pragma unroll
    for (int ks = 0; ks < 4; ++ks) {
        const int k0 = ks * 32 + lhi * 8;
        bf16x8 am[4], bn[4];
#pragma unroll
        for (int mt = 0; mt < 4; ++mt) {
            int row = rowbase + mt * 16 + l15;
            if (row >= NN) row = NN - 1;
            if constexpr (std::is_same<AT, __bf16>::value) {
                am[mt] = *(const bf16x8*)(A + (size_t)row * 128 + k0);
            } else {
                const float4* ap = (const float4*)(A + (size_t)row * 128 + k0);
                float4 f0 = ap[0], f1 = ap[1];
                bf16x8 a;
                a[0]=(__bf16)f0.x; a[1]=(__bf16)f0.y; a[2]=(__bf16)f0.z; a[3]=(__bf16)f0.w;
                a[4]=(__bf16)f1.x; a[5]=(__bf16)f1.y; a[6]=(__bf16)f1.z; a[7]=(__bf16)f1.w;
                am[mt] = a;
            }
        }
#pragma unroll
        for (int nt = 0; nt < 4; ++nt) {
            int n = wave * 64 + nt * 16 + l15;
            bn[nt] = *(const bf16x8*)(W1T + (size_t)n * 128 + k0);
        }
#pragma unroll
        for (int mt = 0; mt < 4; ++mt)
#pragma unroll
            for (int nt = 0; nt < 4; ++nt)
                acc1[mt][nt] = __builtin_amdgcn_mfma_f32_16x16x32_bf16(am[mt], bn[nt], acc1[mt][nt], 0, 0, 0);
    }

#pragma unroll
    for (int nt = 0; nt < 4; ++nt) {
        int n = wave * 64 + nt * 16 + l15;
        float bias = b1[n];
#pragma unroll
        for (int mt = 0; mt < 4; ++mt)
#pragma unroll
            for (int r = 0; r < 4; ++r) {
                float h = acc1[mt][nt][r] + bias;
                Hl[mt * 16 + lhi * 4 + r][n] = (__bf16)fmaxf(h, 0.0f);
            }
    }
    __syncthreads();

    f32x4 acc2[4][2] = {};
#pragma unroll
    for (int ks = 0; ks < 8; ++ks) {
        const int k0 = ks * 32 + lhi * 8;
        bf16x8 ha[4], wb[2];
#pragma unroll
        for (int mt = 0; mt < 4; ++mt)
            ha[mt] = *(const bf16x8*)(&Hl[mt * 16 + l15][k0]);
#pragma unroll
        for (int nt = 0; nt < 2; ++nt) {
            int n = wave * 32 + nt * 16 + l15;
            wb[nt] = *(const bf16x8*)(W2T + (size_t)n * 256 + k0);
        }
#pragma unroll
        for (int mt = 0; mt < 4; ++mt)
#pragma unroll
            for (int nt = 0; nt < 2; ++nt)
                acc2[mt][nt] = __builtin_amdgcn_mfma_f32_16x16x32_bf16(ha[mt], wb[nt], acc2[mt][nt], 0, 0, 0);
    }

#pragma unroll
    for (int nt = 0; nt < 2; ++nt) {
        int n = wave * 32 + nt * 16 + l15;
        float bias = b2[n];
#pragma unroll
        for (int mt = 0; mt < 4; ++mt)
#pragma unroll
            for (int r = 0; r < 4; ++r) {
                int row = rowbase + mt * 16 + lhi * 4 + r;
                if (row < NN) out[(size_t)row * 128 + n] = acc2[mt][nt][r] + bias;
            }
    }
}

extern "C" void kernel_launch(void* const* d_in, const int* in_sizes, int n_in,
                              void* d_out, int out_size, void* d_ws, size_t ws_size,
                              hipStream_t stream) {
    const float* x    = (const float*)d_in[0];
    const float* ev   = (const float*)d_in[1];
    const float* W1   = (const float*)d_in[2];
    const float* b1   = (const float*)d_in[3];
    const float* W2   = (const float*)d_in[4];
    const float* b2   = (const float*)d_in[5];
    const float* eps  = (const float*)d_in[6];
    const int*   esrc = (const int*)d_in[7];
    const int*   edst = (const int*)d_in[8];
    float* out = (float*)d_out;

    char* ws = (char*)d_ws;
    size_t off = 0;
    auto alloc = [&](size_t bytes) { void* p = ws + off; off += (bytes + 511) & ~size_t(511); return p; };

    __bf16* W1T   = (__bf16*)alloc(128 * 256 * sizeof(__bf16));
    __bf16* W2T   = (__bf16*)alloc(128 * 256 * sizeof(__bf16));
    int* cnt8     = (int*)  alloc((size_t)NN * 8 * sizeof(int));
    int* node_off = (int*)  alloc((NN + 1) * sizeof(int));
    int* cursor   = (int*)  alloc((NN + 1) * sizeof(int));
    int* bsum     = (int*)  alloc(NB1 * sizeof(int));
    int* boff     = (int*)  alloc(NB1 * sizeof(int));
    int2* pairs   = (int2*) alloc(NE * sizeof(int2));
    unsigned* xb  = (unsigned*)alloc((size_t)NN * 64 * sizeof(unsigned));   // bf16 x
    unsigned* AXb = (unsigned*)alloc((size_t)NN * 64 * sizeof(unsigned));   // bf16 AX
    bool csr_ok = (off <= ws_size);

    int nblk = (NN + 63) / 64;   // 1563
    if (csr_ok) {
        int cblocks = 128 + (NN * 32 + 255) / 256;   // weights + x converts
        convert_kernel<<<cblocks, 256, 0, stream>>>(W1, W2, W1T, W2T, (const float4*)x, (uint2*)xb);
        hipMemsetAsync(cnt8, 0, (size_t)NN * 8 * sizeof(int), stream);
        hist_kernel8<<<2048, 256, 0, stream>>>(edst, cnt8);
        scan_block_sums<<<NB1, 256, 0, stream>>>(cnt8, bsum);
        scan_partials<<<1, 512, 0, stream>>>(bsum, boff);
        scan_write_offsets<<<NB1, 256, 0, stream>>>(cnt8, boff, node_off, cursor);
        reorder_xcd_kernel<<<2048, 256, 0, stream>>>(esrc, edst, ev, cursor, pairs);
        gather_reduce_kernel<<<(NN * 64 + 255) / 256, 256, 0, stream>>>(
            xb, node_off, pairs, eps, (uint2*)AXb);
        mlp_kernel<__bf16><<<nblk, 256, 0, stream>>>((const __bf16*)AXb, W1T, W2T, b1, b2, out);
    } else {
        // fallback: atomic scatter path (fp32 AX in d_out)
        __bf16* W1Tf = (__bf16*)ws;
        __bf16* W2Tf = W1Tf + 128 * 256;
        convert_kernel<<<128, 256, 0, stream>>>(W1, W2, W1Tf, W2Tf, (const float4*)x, (uint2*)nullptr);
        int n4 = NN * 128 / 4;
        init_ax_kernel<<<(n4 + 255) / 256, 256, 0, stream>>>((const float4*)x, (float4*)out, eps, n4);
        scatter_kernel<<<(NE * 64u) / 256u, 256, 0, stream>>>((const float2*)x, ev, esrc, edst, out);
        mlp_kernel<float><<<nblk, 256, 0, stream>>>(out, W1Tf, W2Tf, b1, b2, out);
    }
}